// Round 1
// 105.815 us; speedup vs baseline: 1.0577x; 1.0577x over previous
//
#include <hip/hip_runtime.h>
#include <math.h>

#define BQ   4
#define QN   256
#define KN   1024
#define DIN  256     // Q_SIZE == K_SIZE == V_SIZE
#define HD   128     // H

// C2 = 2*log2(e): exp2(C2*x) = e^{2x}
#define C2F   2.8853900817779268f
#define NL2E  (-2.8853900817779268f)

// ---------------------------------------------------------------------------
// Kernel 1: projections as tiled GEMM, outputs in EXP2 DOMAIN (verified R8):
//   Eq  [b*QN+q][h]    = exp2(C2*qp)
//   EkT4[b][h/4][k][4] = exp2(C2*kp)   (4 consecutive h per float4)
// ---------------------------------------------------------------------------
__global__ __launch_bounds__(256, 2) void proj_kernel(const float* __restrict__ queries,
                                                      const float* __restrict__ keys,
                                                      const float* __restrict__ W_q,
                                                      const float* __restrict__ W_k,
                                                      float* __restrict__ Eq,
                                                      float* __restrict__ EkT4) {
    __shared__ float xT[32][18];    // [k][row], 16 rows + pad
    __shared__ float WT[32][136];   // [k][h]

    const int t = threadIdx.x;
    const int row0 = blockIdx.x * 16;
    const bool is_q = row0 < BQ * QN;
    const float* x = is_q ? queries : keys;
    const float* W = is_q ? W_q : W_k;
    const int xr0 = is_q ? row0 : row0 - BQ * QN;

    const int h0 = (t & 31) * 4;        // 4 h columns
    const int r0 = (t >> 5) * 2;        // 2 rows

    float acc[2][4];
#pragma unroll
    for (int r = 0; r < 2; r++)
#pragma unroll
        for (int c = 0; c < 4; c++) acc[r][c] = 0.f;

    for (int ks = 0; ks < DIN; ks += 32) {
        __syncthreads();
        if (t < 128) {   // x[16 rows][32 k] -> xT[k][row]
            const int r = t >> 3, k4 = (t & 7) * 4;
            float4 xv = *(const float4*)(x + (size_t)(xr0 + r) * DIN + ks + k4);
            xT[k4 + 0][r] = xv.x; xT[k4 + 1][r] = xv.y;
            xT[k4 + 2][r] = xv.z; xT[k4 + 3][r] = xv.w;
        }
#pragma unroll
        for (int u = 0; u < 4; u++) {   // W[128 h][32 k] -> WT[k][h]
            const int h = (t >> 3) + 32 * u, k4 = (t & 7) * 4;
            float4 wv = *(const float4*)(W + (size_t)h * DIN + ks + k4);
            WT[k4 + 0][h] = wv.x; WT[k4 + 1][h] = wv.y;
            WT[k4 + 2][h] = wv.z; WT[k4 + 3][h] = wv.w;
        }
        __syncthreads();
#pragma unroll
        for (int kk = 0; kk < 32; kk++) {
            float2 xv = *(const float2*)&xT[kk][r0];
            float4 wv = *(const float4*)&WT[kk][h0];
            const float xr[2] = {xv.x, xv.y};
            const float wc[4] = {wv.x, wv.y, wv.z, wv.w};
#pragma unroll
            for (int r = 0; r < 2; r++)
#pragma unroll
                for (int c = 0; c < 4; c++)
                    acc[r][c] = __builtin_fmaf(xr[r], wc[c], acc[r][c]);
        }
    }

    if (is_q) {
#pragma unroll
        for (int r = 0; r < 2; r++) {
            float4 o;
            o.x = __builtin_amdgcn_exp2f(C2F * acc[r][0]);
            o.y = __builtin_amdgcn_exp2f(C2F * acc[r][1]);
            o.z = __builtin_amdgcn_exp2f(C2F * acc[r][2]);
            o.w = __builtin_amdgcn_exp2f(C2F * acc[r][3]);
            *(float4*)(Eq + (size_t)(row0 + r0 + r) * HD + h0) = o;
        }
    } else {
        const int krow = row0 - BQ * QN;
        const int b = krow >> 10, k0 = (krow & (KN - 1)) + r0;
        const int h4 = t & 31;                      // = h0/4
#pragma unroll
        for (int r = 0; r < 2; r++) {
            float4 o;
            o.x = __builtin_amdgcn_exp2f(C2F * acc[r][0]);
            o.y = __builtin_amdgcn_exp2f(C2F * acc[r][1]);
            o.z = __builtin_amdgcn_exp2f(C2F * acc[r][2]);
            o.w = __builtin_amdgcn_exp2f(C2F * acc[r][3]);
            *(float4*)(EkT4 + ((size_t)(b * 32 + h4) * KN + k0 + r) * 4) = o;
        }
    }
}

// ---------------------------------------------------------------------------
// Kernel 2: scores -> unnormalized e + per-chunk row sums.
// R13: runtime work-compaction. Only ACTIVE (b, q-tile, 64-k-chunk) triples
// get a block (enumerated via valid_lens prefix sums computed per-block from
// 4 scalar loads); chunk narrowed 128->64 k for finer load balance. Active
// items ~ sum_b ceil(valid/64)*32 spread evenly over CUs instead of the old
// fixed c=blk>>7 mapping that stacked 4 always-active low-c waves per SIMD
// (makespan ~10us) while high-c blocks early-exited with nothing to do.
// Grid = worst-case 4*32*16 = 2048; blocks past the live count exit in ~10
// scalar ops. partial widened to 16 chunk slots; inactive slots are NEVER
// written (av_kernel sums only nc = ceil(valid/64) entries).
// ---------------------------------------------------------------------------
__global__ __launch_bounds__(256, 4) void score_kernel(const float* __restrict__ Eq,
                                                       const float* __restrict__ EkT4,
                                                       const int* __restrict__ valid_lens,
                                                       const float* __restrict__ w_v,
                                                       float* __restrict__ attn,
                                                       float* __restrict__ partial) {
    __shared__ float s_w[HD];
    __shared__ float s_pq[HD][8];
    __shared__ float s_part[4][8][64];

    // --- compaction: map blockIdx.x -> (b, q0, c) over active chunks only ---
    const int v0 = valid_lens[0], v1 = valid_lens[1];
    const int v2 = valid_lens[2], v3 = valid_lens[3];
    const int e0 = 32 * ((v0 + 63) >> 6);
    const int e1 = e0 + 32 * ((v1 + 63) >> 6);
    const int e2 = e1 + 32 * ((v2 + 63) >> 6);
    const int e3 = e2 + 32 * ((v3 + 63) >> 6);
    const int j = blockIdx.x;
    if (j >= e3) return;                 // block-uniform: no barrier divergence
    int b, valid, jj;
    if (j < e0)      { b = 0; valid = v0; jj = j; }
    else if (j < e1) { b = 1; valid = v1; jj = j - e0; }
    else if (j < e2) { b = 2; valid = v2; jj = j - e1; }
    else             { b = 3; valid = v3; jj = j - e2; }
    const int q0 = (jj & 31) * 8;        // q-tile fastest: 32 blocks share an
    const int c  = jj >> 5;              // EkT4 chunk back-to-back (L2 reuse)

    const int t = threadIdx.x;
    const int l = t & 63;                // k within chunk
    const int w = t >> 6;                // wave id = h quarter (32 h each)
    const int k = c * 64 + l;

    if (t < HD) s_w[t] = w_v[t];
    {
        const int h = t & 127;
#pragma unroll
        for (int jq = 0; jq < 4; jq++) {
            const int q = (t >> 7) * 4 + jq;
            s_pq[h][q] = Eq[(size_t)(b * QN + q0 + q) * HD + h];
        }
    }
    __syncthreads();

    // 4 h per dwordx4: quad index = b*32 + w*8 + i
    const float4* kcol = (const float4*)EkT4 + ((size_t)(b * 32 + w * 8) * KN + k);
    float acc[8] = {0.f, 0.f, 0.f, 0.f, 0.f, 0.f, 0.f, 0.f};

#pragma unroll
    for (int i = 0; i < 8; i++) {
        float4 ek4 = kcol[(size_t)i * KN];
        const int hb = w * 32 + i * 4;
        const float ekv[4] = {ek4.x, ek4.y, ek4.z, ek4.w};
#pragma unroll
        for (int jh = 0; jh < 4; jh++) {
            const float ek = ekv[jh];
            const float wv = s_w[hb + jh];
            float4 p0 = *(const float4*)&s_pq[hb + jh][0];
            float4 p1 = *(const float4*)&s_pq[hb + jh][4];
            acc[0] = __builtin_fmaf(wv, __builtin_amdgcn_rcpf(__builtin_fmaf(ek, p0.x, 1.0f)), acc[0]);
            acc[1] = __builtin_fmaf(wv, __builtin_amdgcn_rcpf(__builtin_fmaf(ek, p0.y, 1.0f)), acc[1]);
            acc[2] = __builtin_fmaf(wv, __builtin_amdgcn_rcpf(__builtin_fmaf(ek, p0.z, 1.0f)), acc[2]);
            acc[3] = __builtin_fmaf(wv, __builtin_amdgcn_rcpf(__builtin_fmaf(ek, p0.w, 1.0f)), acc[3]);
            acc[4] = __builtin_fmaf(wv, __builtin_amdgcn_rcpf(__builtin_fmaf(ek, p1.x, 1.0f)), acc[4]);
            acc[5] = __builtin_fmaf(wv, __builtin_amdgcn_rcpf(__builtin_fmaf(ek, p1.y, 1.0f)), acc[5]);
            acc[6] = __builtin_fmaf(wv, __builtin_amdgcn_rcpf(__builtin_fmaf(ek, p1.z, 1.0f)), acc[6]);
            acc[7] = __builtin_fmaf(wv, __builtin_amdgcn_rcpf(__builtin_fmaf(ek, p1.w, 1.0f)), acc[7]);
        }
    }

#pragma unroll
    for (int q = 0; q < 8; q++) s_part[w][q][l] = acc[q];
    __syncthreads();

    // epilogue: each wave finishes 2 q rows; full-wave shuffle row-sum
#pragma unroll
    for (int jq = 0; jq < 2; jq++) {
        const int q = w * 2 + jq;
        float tot = s_part[0][q][l] + s_part[1][q][l] + s_part[2][q][l] + s_part[3][q][l];
        float e = (k < valid) ? __builtin_amdgcn_exp2f(NL2E * tot) : 0.f;
        attn[(size_t)(b * QN + q0 + q) * KN + k] = e;
        float r = e;
#pragma unroll
        for (int off = 32; off > 0; off >>= 1) r += __shfl_xor(r, off, 64);
        if (l == 0) partial[(size_t)(b * QN + q0 + q) * 16 + c] = r;
    }
}

// ---------------------------------------------------------------------------
// Kernel 3: out = normalize(e) @ values, register-prefetched tiled GEMM.
// R12 structure; R13: partial rows are now [16] wide and only the first
// nc = ceil(valid/64) entries are written by score -> masked sum here.
// ---------------------------------------------------------------------------
__global__ __launch_bounds__(256, 2) void av_kernel(const float* __restrict__ attn,
                                                    const float* __restrict__ partial,
                                                    const float* __restrict__ values,
                                                    const int* __restrict__ valid_lens,
                                                    float* __restrict__ out) {
    __shared__ float s_aT[32][20];      // [kk][q], 16 q + pad
    __shared__ float s_v[32][36];       // [kk][v]
    __shared__ float s_red[8][16][37];  // per-k-slice partials, conflict-padded
    __shared__ float s_inv[16];

    const int blk = blockIdx.x;
    const int b = blk & 3;
    const int qt = (blk >> 2) & 15;
    const int vt = blk >> 6;
    const int t = threadIdx.x;
    const int q0 = qt * 16, v0 = vt * 32;
    const int valid = valid_lens[b];
    const int T = (valid + 31) >> 5;    // k-tiles (valid >= 1 so T >= 1)

    if (t < 16) {
        const float* pr = partial + (size_t)(b * QN + q0 + t) * 16;
        const int nc = (valid + 63) >> 6;   // only these slots were written
        float s = 0.f;
        for (int cc = 0; cc < nc; cc++) s += pr[cc];
        s_inv[t] = 1.0f / s;
    }

    // staging: t<128 loads attn[q0 + (t>>3)][kt + (t&7)*4 ..+3] (transposed);
    //          all 256 load V[kt + (t>>3)][v0 + (t&7)*4 ..+3]
    const int sr = t >> 3, sc = (t & 7) * 4;
    const float* abase = attn + (size_t)(b * QN + q0 + (sr & 15)) * KN + sc;
    const float* vbase = values + ((size_t)b * KN + sr) * DIN + v0 + sc;

    const int ks = t >> 5;              // 8 k-slices of 4
    const int qh = (t >> 3) & 3;        // 4 q-groups of 4
    const int vh = t & 7;               // 8 v-groups of 4

    float acc[4][4];
#pragma unroll
    for (int r = 0; r < 4; r++)
#pragma unroll
        for (int c = 0; c < 4; c++) acc[r][c] = 0.f;

    float4 ra = *(const float4*)abase;      // prefetch tile 0
    float4 rv = *(const float4*)vbase;

    for (int tile = 0; tile < T; tile++) {
        __syncthreads();
        if (t < 128) {
            s_aT[sc + 0][sr] = ra.x;        // attn transposed -> [kk][q]
            s_aT[sc + 1][sr] = ra.y;
            s_aT[sc + 2][sr] = ra.z;
            s_aT[sc + 3][sr] = ra.w;
        }
        *(float4*)&s_v[sr][sc] = rv;
        __syncthreads();
        if (tile + 1 < T) {                 // issue next tile's loads now
            ra = *(const float4*)(abase + (tile + 1) * 32);
            rv = *(const float4*)(vbase + (size_t)(tile + 1) * 32 * DIN);
        }
#pragma unroll
        for (int i = 0; i < 4; i++) {
            const int kk = ks * 4 + i;
            float4 aq = *(const float4*)&s_aT[kk][qh * 4];
            float4 vv = *(const float4*)&s_v[kk][vh * 4];
            const float ar[4] = {aq.x, aq.y, aq.z, aq.w};
            const float vc[4] = {vv.x, vv.y, vv.z, vv.w};
#pragma unroll
            for (int r = 0; r < 4; r++)
#pragma unroll
                for (int c = 0; c < 4; c++)
                    acc[r][c] = __builtin_fmaf(ar[r], vc[c], acc[r][c]);
        }
    }

#pragma unroll
    for (int r = 0; r < 4; r++)
        *(float4*)&s_red[ks][qh * 4 + r][vh * 4] =
            make_float4(acc[r][0], acc[r][1], acc[r][2], acc[r][3]);
    __syncthreads();

    if (t < 128) {   // epilogue: sum 8 k-slices, normalize, float4 store
        const int q = t >> 3, v4 = (t & 7) * 4;
        float4 o = {0.f, 0.f, 0.f, 0.f};
#pragma unroll
        for (int s = 0; s < 8; s++) {
            float4 r = *(const float4*)&s_red[s][q][v4];
            o.x += r.x; o.y += r.y; o.z += r.z; o.w += r.w;
        }
        const float inv = s_inv[q];
        o.x *= inv; o.y *= inv; o.z *= inv; o.w *= inv;
        *(float4*)(out + (size_t)(b * QN + q0 + q) * DIN + v0 + v4) = o;
    }
}

extern "C" void kernel_launch(void* const* d_in, const int* in_sizes, int n_in,
                              void* d_out, int out_size, void* d_ws, size_t ws_size,
                              hipStream_t stream) {
    const float* queries    = (const float*)d_in[0];
    const float* keys       = (const float*)d_in[1];
    const float* values     = (const float*)d_in[2];
    const int*   valid_lens = (const int*)d_in[3];
    const float* W_q        = (const float*)d_in[4];
    const float* W_k        = (const float*)d_in[5];
    const float* w_v        = (const float*)d_in[6];
    float* out = (float*)d_out;

    float* Eq      = (float*)d_ws;                    // [B*QN][HD]     512 KB
    float* EkT4    = Eq + (size_t)BQ * QN * HD;       // [B][32][KN][4]   2 MB
    float* attn    = EkT4 + (size_t)BQ * HD * KN;     // [B*QN][KN]       4 MB
    float* partial = attn + (size_t)BQ * QN * KN;     // [B*QN][16]      64 KB

    proj_kernel<<<(BQ * QN + BQ * KN) / 16, 256, 0, stream>>>(queries, keys, W_q, W_k, Eq, EkT4);
    score_kernel<<<BQ * (QN / 8) * 16, 256, 0, stream>>>(Eq, EkT4, valid_lens, w_v, attn, partial);
    av_kernel<<<BQ * 16 * 8, 256, 0, stream>>>(attn, partial, values, valid_lens, out);
}